// Round 1
// 549.193 us; speedup vs baseline: 1.4776x; 1.4776x over previous
//
#include <hip/hip_runtime.h>
#include <cstdint>
#include <cstddef>

#define D_DIM 256
#define K_CODES 4096
#define N_ROWS 16384
#define NORM_ROWS_PER_BLK 32

typedef __attribute__((ext_vector_type(4))) int   i32x4;
typedef __attribute__((ext_vector_type(4))) float f32x4;

// ---- bf16 helpers (RNE) ----
__device__ __forceinline__ unsigned short f2bf(float x) {
    const unsigned int u = __float_as_uint(x);
    return (unsigned short)((u + 0x7fffu + ((u >> 16) & 1u)) >> 16);
}
__device__ __forceinline__ float bf2f(unsigned short h) {
    return __uint_as_float((unsigned int)h << 16);
}

// ---- async global->LDS, 16B per lane (dest is wave-uniform base + lane*16) ----
__device__ __forceinline__ void gload16(const unsigned short* g, unsigned short* l) {
    __builtin_amdgcn_global_load_lds(
        (const __attribute__((address_space(1))) void*)g,
        (__attribute__((address_space(3))) void*)l, 16, 0, 0);
}

// ---- inline-asm MFMA: D = A*B + D (gfx950, bf16 16x16x32, 4 VGPR frags) ----
#define MFMA(c, a, b) \
    asm volatile("v_mfma_f32_16x16x32_bf16 %0, %1, %2, %0" : "+v"(c) : "v"(a), "v"(b))

// ---- numpy-pairwise sum of squares of a 128-float block (fp32, no contraction) ----
__device__ __forceinline__ float np_sumsq_128(const float* __restrict__ a)
{
    float r[8];
    #pragma unroll
    for (int j = 0; j < 8; ++j) r[j] = __fmul_rn(a[j], a[j]);
    #pragma unroll
    for (int i = 8; i < 128; i += 8)
        #pragma unroll
        for (int j = 0; j < 8; ++j)
            r[j] = __fadd_rn(r[j], __fmul_rn(a[i + j], a[i + j]));
    return __fadd_rn(__fadd_rn(__fadd_rn(r[0], r[1]), __fadd_rn(r[2], r[3])),
                     __fadd_rn(__fadd_rn(r[4], r[5]), __fadd_rn(r[6], r[7])));
}

// ---- row L2-normalize (numpy-exact) + emit bf16 hi/lo split planes ----
__global__ __launch_bounds__(256) void norm_rows_np_kernel(
    const float* __restrict__ src, float* __restrict__ dst,
    unsigned short* __restrict__ dsth, unsigned short* __restrict__ dstl)
{
    __shared__ float lds[NORM_ROWS_PER_BLK * D_DIM];
    __shared__ float nrm[NORM_ROWS_PER_BLK];
    const int tid = threadIdx.x;
    const size_t base = (size_t)blockIdx.x * NORM_ROWS_PER_BLK * D_DIM;

    #pragma unroll
    for (int i = 0; i < NORM_ROWS_PER_BLK; ++i)
        lds[i * 256 + tid] = src[base + i * 256 + tid];
    __syncthreads();

    if (tid < NORM_ROWS_PER_BLK) {
        const float* row = &lds[tid * D_DIM];
        const float tot = __fadd_rn(np_sumsq_128(row), np_sumsq_128(row + 128));
        const float n = (float)sqrt((double)tot);
        nrm[tid] = fmaxf(n, 1e-12f);
    }
    __syncthreads();

    #pragma unroll
    for (int i = 0; i < NORM_ROWS_PER_BLK; ++i) {
        const int e = i * 256 + tid;
        const float v = lds[e] / nrm[i];
        dst[base + e] = v;
        const unsigned short h = f2bf(v);
        dsth[base + e] = h;
        dstl[base + e] = f2bf(v - bf2f(h));
    }
}

// ---------------- split-bf16 MFMA GEMM: C[N,K] ~= A[N,D] * B[K,D]^T ----------------
// cos ~ Ah*Bh + Ah*Bl + Al*Bh (3 bf16 MFMAs, fp32 acc). |err| <= ~7e-5.
// 128x128 tile, BK=32, 4 waves (2x2), each wave 64x64 via 4x4 frags of 16x16x32.
// LDS: 4 planes of [128][32] bf16 (8KB each, 32KB). global_load_lds width=16 with
// source-side XOR swizzle g ^= (row>>1)&3 -> conflict-free ds_read_b128 on read side.
__global__ __launch_bounds__(256) void gemm_bf16x3_kernel(
    const unsigned short* __restrict__ Ah, const unsigned short* __restrict__ Al,
    const unsigned short* __restrict__ Bh, const unsigned short* __restrict__ Bl,
    float* __restrict__ C)
{
    __shared__ __align__(16) unsigned short smem[4 * 4096]; // Ah|Al|Bh|Bl tiles

    const int tid  = threadIdx.x;
    const int lane = tid & 63;
    const int wv   = tid >> 6;
    const int wr   = wv >> 1, wc = wv & 1;
    const int bm   = blockIdx.y * 128, bn = blockIdx.x * 128;

    // staging geometry: 512 granules (16B) per plane = 2 parts x 256 threads
    const int og0 = tid, og1 = 256 + tid;
    const int row0 = og0 >> 2, row1 = og1 >> 2;
    const int g0 = (og0 & 3) ^ ((row0 >> 1) & 3);   // source granule for linear slot
    const int g1 = (og1 & 3) ^ ((row1 >> 1) & 3);
    const size_t asrc0 = (size_t)(bm + row0) * D_DIM + g0 * 8;
    const size_t asrc1 = (size_t)(bm + row1) * D_DIM + g1 * 8;
    const size_t bsrc0 = (size_t)(bn + row0) * D_DIM + g0 * 8;
    const size_t bsrc1 = (size_t)(bn + row1) * D_DIM + g1 * 8;
    unsigned short* lds0 = smem + wv * 512;          // wave-uniform, part 0
    unsigned short* lds1 = smem + 2048 + wv * 512;   // wave-uniform, part 1

    // fragment read byte-offsets within a plane (swizzled)
    int aoff[4], boff[4];
    #pragma unroll
    for (int i = 0; i < 4; ++i) {
        const int ar = wr * 64 + i * 16 + (lane & 15);
        aoff[i] = ar * 64 + ((((lane >> 4) ^ ((ar >> 1) & 3)) & 3) << 4);
        const int br = wc * 64 + i * 16 + (lane & 15);
        boff[i] = br * 64 + ((((lane >> 4) ^ ((br >> 1) & 3)) & 3) << 4);
    }
    const char* sA = (const char*)smem;

    f32x4 acc[4][4] = {};

    for (int k0 = 0; k0 < D_DIM; k0 += 32) {
        __syncthreads();                       // previous tile fully consumed
        gload16(Ah + asrc0 + k0, lds0);
        gload16(Ah + asrc1 + k0, lds1);
        gload16(Al + asrc0 + k0, lds0 + 4096);
        gload16(Al + asrc1 + k0, lds1 + 4096);
        gload16(Bh + bsrc0 + k0, lds0 + 8192);
        gload16(Bh + bsrc1 + k0, lds1 + 8192);
        gload16(Bl + bsrc0 + k0, lds0 + 12288);
        gload16(Bl + bsrc1 + k0, lds1 + 12288);
        __syncthreads();                       // vmcnt(0) drain + barrier

        i32x4 ah[4], al[4], bh[4], bl[4];
        #pragma unroll
        for (int i = 0; i < 4; ++i) {
            ah[i] = *(const i32x4*)(sA +         aoff[i]);
            al[i] = *(const i32x4*)(sA +  8192 + aoff[i]);
            bh[i] = *(const i32x4*)(sA + 16384 + boff[i]);
            bl[i] = *(const i32x4*)(sA + 24576 + boff[i]);
        }
        #pragma unroll
        for (int i = 0; i < 4; ++i)
            #pragma unroll
            for (int j = 0; j < 4; ++j)
                MFMA(acc[i][j], ah[i], bh[j]);
        #pragma unroll
        for (int i = 0; i < 4; ++i)
            #pragma unroll
            for (int j = 0; j < 4; ++j)
                MFMA(acc[i][j], ah[i], bl[j]);
        #pragma unroll
        for (int i = 0; i < 4; ++i)
            #pragma unroll
            for (int j = 0; j < 4; ++j)
                MFMA(acc[i][j], al[i], bh[j]);
    }
    asm volatile("s_nop 7\n\ts_nop 7\n\ts_nop 7");   // MFMA->VALU read fence

    // C/D layout: col = lane&15, row = (lane>>4)*4 + reg   [m89-verified]
    #pragma unroll
    for (int i = 0; i < 4; ++i) {
        const int r0 = bm + wr * 64 + i * 16 + ((lane >> 4) << 2);
        #pragma unroll
        for (int j = 0; j < 4; ++j) {
            const int c0 = bn + wc * 64 + j * 16 + (lane & 15);
            #pragma unroll
            for (int r = 0; r < 4; ++r)
                C[(size_t)(r0 + r) * K_CODES + c0] = acc[i][j][r];
        }
    }
}

// ---------------- per-row: windowed-exact argmin, softmax, gather ----------------
// P holds approximate cos (|err|<=~7e-5). Candidates with d_ap <= min+TAU are
// rescored with the EXACT sequential-fma fp32 dot (identical arithmetic to the
// previously-passing fp32 GEMM), first-index tie-break => idx bit-equivalent.
__global__ __launch_bounds__(256) void rowpass_kernel(
    float* __restrict__ P,            // [N,K] in: cos(approx), out: soft_probs
    const float* __restrict__ cbn,    // [K,D] normalized codebook (fp32)
    float* __restrict__ xq,           // [N,D] in: x_n, out: quantized
    float* __restrict__ idx_out,      // [N]
    float* __restrict__ counts,       // [K]
    float* __restrict__ rowloss)      // [N]
{
    const int row = blockIdx.x;
    const int t = threadIdx.x;
    float4* rp = (float4*)(P + (size_t)row * K_CODES);

    __shared__ float sf[4];
    __shared__ float sbd[4];
    __shared__ float s_x[D_DIM];
    __shared__ int   s_cnt;
    __shared__ int   s_cand[128];
    __shared__ float s_dex[128];
    __shared__ int   s_besti;

    float vals[16];
    #pragma unroll
    for (int j = 0; j < 4; ++j) {
        const float4 v = rp[j * 256 + t];
        vals[j * 4 + 0] = v.x; vals[j * 4 + 1] = v.y;
        vals[j * 4 + 2] = v.z; vals[j * 4 + 3] = v.w;
    }

    s_x[t] = xq[(size_t)row * D_DIM + t];
    if (t == 0) s_cnt = 0;

    // block max-cos (softmax) and approx min-dist
    float m = -1e30f, bd = 3.402823466e+38f;
    #pragma unroll
    for (int i = 0; i < 16; ++i) {
        m = fmaxf(m, vals[i]);
        bd = fminf(bd, 2.0f - 2.0f * vals[i]);
    }
    #pragma unroll
    for (int off = 32; off > 0; off >>= 1) {
        m  = fmaxf(m,  __shfl_down(m,  off));
        bd = fminf(bd, __shfl_down(bd, off));
    }
    if ((t & 63) == 0) { sf[t >> 6] = m; sbd[t >> 6] = bd; }
    __syncthreads();
    const float M  = fmaxf(fmaxf(sf[0], sf[1]), fmaxf(sf[2], sf[3]));
    const float fb = fminf(fminf(sbd[0], sbd[1]), fminf(sbd[2], sbd[3]));

    // ---- candidate window (TAU = 2^-7 >> 2 * max approx error) ----
    const float TAU = 0.0078125f;
    #pragma unroll
    for (int i = 0; i < 16; ++i) {
        const float d = 2.0f - 2.0f * vals[i];
        if (d <= fb + TAU) {
            const int p = atomicAdd(&s_cnt, 1);
            if (p < 128) s_cand[p] = ((i >> 2) * 256 + t) * 4 + (i & 3);
        }
    }
    __syncthreads();
    const int cnt = min(s_cnt, 128);
    if (cnt == 1) {
        if (t == 0) s_besti = s_cand[0];
    } else {
        if (t < cnt) {                 // exact rescore, sequential fma k=0..255
            const float* cb = cbn + (size_t)s_cand[t] * D_DIM;
            float acc = 0.0f;
            for (int k = 0; k < D_DIM; ++k) acc = fmaf(s_x[k], cb[k], acc);
            s_dex[t] = 2.0f - 2.0f * acc;
        }
        __syncthreads();
        if (t == 0) {                  // first-index tie-break
            float bdx = 3.402823466e+38f; int bii = 0x7fffffff;
            for (int c = 0; c < cnt; ++c) {
                const float d = s_dex[c]; const int ii = s_cand[c];
                if (d < bdx || (d == bdx && ii < bii)) { bdx = d; bii = ii; }
            }
            s_besti = bii;
        }
    }
    __syncthreads();
    const int besti = s_besti;

    // softmax: p_i = exp(20*(cos_i - M)) / sum
    float esum = 0.0f;
    #pragma unroll
    for (int i = 0; i < 16; ++i) {
        vals[i] = __expf(20.0f * (vals[i] - M));
        esum += vals[i];
    }
    #pragma unroll
    for (int off = 32; off > 0; off >>= 1) esum += __shfl_down(esum, off);
    __syncthreads();
    if ((t & 63) == 0) sf[t >> 6] = esum;
    __syncthreads();
    const float inv = 1.0f / (sf[0] + sf[1] + sf[2] + sf[3]);
    #pragma unroll
    for (int j = 0; j < 4; ++j) {
        rp[j * 256 + t] = make_float4(vals[j * 4 + 0] * inv, vals[j * 4 + 1] * inv,
                                      vals[j * 4 + 2] * inv, vals[j * 4 + 3] * inv);
    }

    // gather quantized row, per-row commitment loss
    const float q = cbn[(size_t)besti * D_DIM + t];
    xq[(size_t)row * D_DIM + t] = q;
    const float dd = q - s_x[t];
    float ls = dd * dd;
    #pragma unroll
    for (int off = 32; off > 0; off >>= 1) ls += __shfl_down(ls, off);
    __syncthreads();
    if ((t & 63) == 0) sf[t >> 6] = ls;
    __syncthreads();
    if (t == 0) {
        rowloss[row] = sf[0] + sf[1] + sf[2] + sf[3];
        idx_out[row] = (float)besti;
        atomicAdd(&counts[besti], 1.0f);
    }
}

// ---------------- finalize: vq_loss scalar + perplexity ----------------
__global__ __launch_bounds__(256) void finalize_kernel(
    const float* __restrict__ rowloss, const float* __restrict__ counts,
    float* __restrict__ out_loss, float* __restrict__ out_ppl)
{
    const int t = threadIdx.x;
    float s = 0.0f;
    for (int i = t; i < N_ROWS; i += 256) s += rowloss[i];
    float e = 0.0f;
    for (int i = t; i < K_CODES; i += 256) {
        const float avg = counts[i] * (1.0f / (float)N_ROWS);
        e += avg * logf(avg + 1e-10f);
    }
    #pragma unroll
    for (int off = 32; off > 0; off >>= 1) {
        s += __shfl_down(s, off);
        e += __shfl_down(e, off);
    }
    __shared__ float sf[4], se[4];
    if ((t & 63) == 0) { sf[t >> 6] = s; se[t >> 6] = e; }
    __syncthreads();
    if (t == 0) {
        out_loss[0] = 0.25f * (sf[0] + sf[1] + sf[2] + sf[3]) /
                      ((float)N_ROWS * (float)D_DIM);
        out_ppl[0] = expf(-(se[0] + se[1] + se[2] + se[3]));
    }
}

extern "C" void kernel_launch(void* const* d_in, const int* in_sizes, int n_in,
                              void* d_out, int out_size, void* d_ws, size_t ws_size,
                              hipStream_t stream) {
    const float* inputs   = (const float*)d_in[0];   // [N, D] raw
    const float* codebook = (const float*)d_in[1];   // [K, D] raw
    float* out = (float*)d_out;

    // output layout (flat, return order)
    float* vq_loss = out;                                   // 1
    float* quant   = out + 1;                               // N*D (also x_n scratch)
    float* probs   = quant + (size_t)N_ROWS * D_DIM;        // N*K
    float* ppl     = probs + (size_t)N_ROWS * K_CODES;      // 1
    float* idxout  = ppl + 1;                               // N

    // workspace layout (~25.3 MB)
    float* cbn     = (float*)d_ws;                          // K*D fp32
    float* counts  = cbn + (size_t)K_CODES * D_DIM;         // K
    float* rowloss = counts + K_CODES;                      // N
    unsigned short* Ah = (unsigned short*)(rowloss + N_ROWS);   // N*D bf16 hi
    unsigned short* Al = Ah + (size_t)N_ROWS * D_DIM;           // N*D bf16 lo
    unsigned short* Bh = Al + (size_t)N_ROWS * D_DIM;           // K*D bf16 hi
    unsigned short* Bl = Bh + (size_t)K_CODES * D_DIM;          // K*D bf16 lo

    hipMemsetAsync(counts, 0, K_CODES * sizeof(float), stream);
    norm_rows_np_kernel<<<K_CODES / NORM_ROWS_PER_BLK, 256, 0, stream>>>(codebook, cbn, Bh, Bl);
    norm_rows_np_kernel<<<N_ROWS / NORM_ROWS_PER_BLK, 256, 0, stream>>>(inputs, quant, Ah, Al);
    gemm_bf16x3_kernel<<<dim3(K_CODES / 128, N_ROWS / 128), 256, 0, stream>>>(Ah, Al, Bh, Bl, probs);
    rowpass_kernel<<<N_ROWS, 256, 0, stream>>>(probs, cbn, quant, idxout, counts, rowloss);
    finalize_kernel<<<1, 256, 0, stream>>>(rowloss, counts, vq_loss, ppl);
}

// Round 2
// 545.437 us; speedup vs baseline: 1.4878x; 1.0069x over previous
//
#include <hip/hip_runtime.h>
#include <cstdint>
#include <cstddef>

#define D_DIM 256
#define K_CODES 4096
#define N_ROWS 16384
#define NORM_ROWS_PER_BLK 32

typedef __attribute__((ext_vector_type(4))) int   i32x4;
typedef __attribute__((ext_vector_type(4))) float f32x4;

// ---- bf16 helpers (RNE) ----
__device__ __forceinline__ unsigned short f2bf(float x) {
    const unsigned int u = __float_as_uint(x);
    return (unsigned short)((u + 0x7fffu + ((u >> 16) & 1u)) >> 16);
}
__device__ __forceinline__ float bf2f(unsigned short h) {
    return __uint_as_float((unsigned int)h << 16);
}

// ---- async global->LDS, 16B per lane (dest is wave-uniform base + lane*16) ----
__device__ __forceinline__ void gload16(const unsigned short* g, unsigned short* l) {
    __builtin_amdgcn_global_load_lds(
        (const __attribute__((address_space(1))) void*)g,
        (__attribute__((address_space(3))) void*)l, 16, 0, 0);
}

// ---- inline-asm MFMA: D = A*B + D (gfx950, bf16 16x16x32, 4 VGPR frags) ----
#define MFMA(c, a, b) \
    asm volatile("v_mfma_f32_16x16x32_bf16 %0, %1, %2, %0" : "+v"(c) : "v"(a), "v"(b))

// ---- numpy-pairwise sum of squares of a 128-float block (fp32, no contraction) ----
__device__ __forceinline__ float np_sumsq_128(const float* __restrict__ a)
{
    float r[8];
    #pragma unroll
    for (int j = 0; j < 8; ++j) r[j] = __fmul_rn(a[j], a[j]);
    #pragma unroll
    for (int i = 8; i < 128; i += 8)
        #pragma unroll
        for (int j = 0; j < 8; ++j)
            r[j] = __fadd_rn(r[j], __fmul_rn(a[i + j], a[i + j]));
    return __fadd_rn(__fadd_rn(__fadd_rn(r[0], r[1]), __fadd_rn(r[2], r[3])),
                     __fadd_rn(__fadd_rn(r[4], r[5]), __fadd_rn(r[6], r[7])));
}

// ---- row L2-normalize (numpy-exact) + emit bf16 hi/lo split planes ----
__global__ __launch_bounds__(256) void norm_rows_np_kernel(
    const float* __restrict__ src, float* __restrict__ dst,
    unsigned short* __restrict__ dsth, unsigned short* __restrict__ dstl)
{
    __shared__ float lds[NORM_ROWS_PER_BLK * D_DIM];
    __shared__ float nrm[NORM_ROWS_PER_BLK];
    const int tid = threadIdx.x;
    const size_t base = (size_t)blockIdx.x * NORM_ROWS_PER_BLK * D_DIM;

    #pragma unroll
    for (int i = 0; i < NORM_ROWS_PER_BLK; ++i)
        lds[i * 256 + tid] = src[base + i * 256 + tid];
    __syncthreads();

    if (tid < NORM_ROWS_PER_BLK) {
        const float* row = &lds[tid * D_DIM];
        const float tot = __fadd_rn(np_sumsq_128(row), np_sumsq_128(row + 128));
        const float n = (float)sqrt((double)tot);
        nrm[tid] = fmaxf(n, 1e-12f);
    }
    __syncthreads();

    #pragma unroll
    for (int i = 0; i < NORM_ROWS_PER_BLK; ++i) {
        const int e = i * 256 + tid;
        const float v = lds[e] / nrm[i];
        dst[base + e] = v;
        const unsigned short h = f2bf(v);
        dsth[base + e] = h;
        dstl[base + e] = f2bf(v - bf2f(h));
    }
}

// ---------------- split-bf16 MFMA GEMM: C[N,K] ~= A[N,D] * B[K,D]^T ----------------
// cos ~ Ah*Bh + Ah*Bl + Al*Bh (3 bf16 MFMAs, fp32 acc). |err| <= ~7e-5.
// 128x128 tile, BK=32, 4 waves (2x2), each wave 64x64 via 4x4 frags of 16x16x32.
// DOUBLE-BUFFERED (T3 minimum 2-phase): STAGE(next) is issued BEFORE the current
// tile's ds_read+MFMA; the single __syncthreads per K-step drains vmcnt AFTER the
// compute phase, hiding the global->LDS latency. LDS: 2 x 4 planes of [128][32]
// bf16 = 64KB. Source-side XOR swizzle g ^= (row>>1)&3 keeps ds_read_b128
// fragment reads bank-conflict-free (global_load_lds dest must stay linear).
__global__ __launch_bounds__(256) void gemm_bf16x3_kernel(
    const unsigned short* __restrict__ Ah, const unsigned short* __restrict__ Al,
    const unsigned short* __restrict__ Bh, const unsigned short* __restrict__ Bl,
    float* __restrict__ C)
{
    __shared__ __align__(16) unsigned short smem[2 * 4 * 4096]; // dbuf x Ah|Al|Bh|Bl

    const int tid  = threadIdx.x;
    const int lane = tid & 63;
    const int wv   = tid >> 6;
    const int wr   = wv >> 1, wc = wv & 1;
    const int bm   = blockIdx.y * 128, bn = blockIdx.x * 128;

    // staging geometry: 512 granules (16B) per plane = 2 parts x 256 threads
    const int og0 = tid, og1 = 256 + tid;
    const int row0 = og0 >> 2, row1 = og1 >> 2;
    const int g0 = (og0 & 3) ^ ((row0 >> 1) & 3);   // source granule for linear slot
    const int g1 = (og1 & 3) ^ ((row1 >> 1) & 3);
    const size_t asrc0 = (size_t)(bm + row0) * D_DIM + g0 * 8;
    const size_t asrc1 = (size_t)(bm + row1) * D_DIM + g1 * 8;
    const size_t bsrc0 = (size_t)(bn + row0) * D_DIM + g0 * 8;
    const size_t bsrc1 = (size_t)(bn + row1) * D_DIM + g1 * 8;

    // fragment read byte-offsets within a plane (swizzled)
    int aoff[4], boff[4];
    #pragma unroll
    for (int i = 0; i < 4; ++i) {
        const int ar = wr * 64 + i * 16 + (lane & 15);
        aoff[i] = ar * 64 + ((((lane >> 4) ^ ((ar >> 1) & 3)) & 3) << 4);
        const int br = wc * 64 + i * 16 + (lane & 15);
        boff[i] = br * 64 + ((((lane >> 4) ^ ((br >> 1) & 3)) & 3) << 4);
    }
    const char* sA = (const char*)smem;

    // stage one 32KB tile-set (all 4 planes) for K-step k0 into buffer buf
    auto stage = [&](int buf, int k0) {
        unsigned short* l0 = smem + buf * 16384 + wv * 512;          // part 0
        unsigned short* l1 = smem + buf * 16384 + 2048 + wv * 512;   // part 1
        gload16(Ah + asrc0 + k0, l0);
        gload16(Ah + asrc1 + k0, l1);
        gload16(Al + asrc0 + k0, l0 + 4096);
        gload16(Al + asrc1 + k0, l1 + 4096);
        gload16(Bh + bsrc0 + k0, l0 + 8192);
        gload16(Bh + bsrc1 + k0, l1 + 8192);
        gload16(Bl + bsrc0 + k0, l0 + 12288);
        gload16(Bl + bsrc1 + k0, l1 + 12288);
    };

    f32x4 acc[4][4] = {};

    stage(0, 0);
    __syncthreads();                 // drain prologue loads (vmcnt(0)) + publish
    int cur = 0;

    #pragma unroll
    for (int t = 0; t < 8; ++t) {
        if (t < 7) stage(cur ^ 1, (t + 1) * 32);   // issue next tile FIRST

        const char* base = sA + cur * 32768;
        i32x4 ah[4], al[4], bh[4], bl[4];
        #pragma unroll
        for (int i = 0; i < 4; ++i) {
            ah[i] = *(const i32x4*)(base +         aoff[i]);
            al[i] = *(const i32x4*)(base +  8192 + aoff[i]);
            bh[i] = *(const i32x4*)(base + 16384 + boff[i]);
            bl[i] = *(const i32x4*)(base + 24576 + boff[i]);
        }
        #pragma unroll
        for (int i = 0; i < 4; ++i)
            #pragma unroll
            for (int j = 0; j < 4; ++j)
                MFMA(acc[i][j], ah[i], bh[j]);
        #pragma unroll
        for (int i = 0; i < 4; ++i)
            #pragma unroll
            for (int j = 0; j < 4; ++j)
                MFMA(acc[i][j], ah[i], bl[j]);
        #pragma unroll
        for (int i = 0; i < 4; ++i)
            #pragma unroll
            for (int j = 0; j < 4; ++j)
                MFMA(acc[i][j], al[i], bh[j]);

        __syncthreads();             // drains next-tile loads (hidden by MFMAs)
        cur ^= 1;                    // and guards buffer reuse
    }
    asm volatile("s_nop 7\n\ts_nop 7\n\ts_nop 7");   // MFMA->VALU read fence

    // C/D layout: col = lane&15, row = (lane>>4)*4 + reg   [m89-verified]
    #pragma unroll
    for (int i = 0; i < 4; ++i) {
        const int r0 = bm + wr * 64 + i * 16 + ((lane >> 4) << 2);
        #pragma unroll
        for (int j = 0; j < 4; ++j) {
            const int c0 = bn + wc * 64 + j * 16 + (lane & 15);
            #pragma unroll
            for (int r = 0; r < 4; ++r)
                C[(size_t)(r0 + r) * K_CODES + c0] = acc[i][j][r];
        }
    }
}

// ---------------- per-row: windowed-exact argmin, softmax, gather ----------------
// P holds approximate cos (|err|<=~7e-5). Candidates with d_ap <= min+TAU are
// rescored with the EXACT sequential-fma fp32 dot (identical arithmetic to the
// original fp32 GEMM), first-index tie-break => idx bit-equivalent.
__global__ __launch_bounds__(256) void rowpass_kernel(
    float* __restrict__ P,            // [N,K] in: cos(approx), out: soft_probs
    const float* __restrict__ cbn,    // [K,D] normalized codebook (fp32)
    float* __restrict__ xq,           // [N,D] in: x_n, out: quantized
    float* __restrict__ idx_out,      // [N]
    float* __restrict__ counts,       // [K]
    float* __restrict__ rowloss)      // [N]
{
    const int row = blockIdx.x;
    const int t = threadIdx.x;
    float4* rp = (float4*)(P + (size_t)row * K_CODES);

    __shared__ float sf[4];
    __shared__ float sbd[4];
    __shared__ float s_x[D_DIM];
    __shared__ int   s_cnt;
    __shared__ int   s_cand[128];
    __shared__ float s_dex[128];
    __shared__ int   s_besti;

    float vals[16];
    #pragma unroll
    for (int j = 0; j < 4; ++j) {
        const float4 v = rp[j * 256 + t];
        vals[j * 4 + 0] = v.x; vals[j * 4 + 1] = v.y;
        vals[j * 4 + 2] = v.z; vals[j * 4 + 3] = v.w;
    }

    s_x[t] = xq[(size_t)row * D_DIM + t];
    if (t == 0) s_cnt = 0;

    // block max-cos (softmax) and approx min-dist
    float m = -1e30f, bd = 3.402823466e+38f;
    #pragma unroll
    for (int i = 0; i < 16; ++i) {
        m = fmaxf(m, vals[i]);
        bd = fminf(bd, 2.0f - 2.0f * vals[i]);
    }
    #pragma unroll
    for (int off = 32; off > 0; off >>= 1) {
        m  = fmaxf(m,  __shfl_down(m,  off));
        bd = fminf(bd, __shfl_down(bd, off));
    }
    if ((t & 63) == 0) { sf[t >> 6] = m; sbd[t >> 6] = bd; }
    __syncthreads();
    const float M  = fmaxf(fmaxf(sf[0], sf[1]), fmaxf(sf[2], sf[3]));
    const float fb = fminf(fminf(sbd[0], sbd[1]), fminf(sbd[2], sbd[3]));

    // ---- candidate window (TAU = 2^-7 >> 2 * max approx error) ----
    const float TAU = 0.0078125f;
    #pragma unroll
    for (int i = 0; i < 16; ++i) {
        const float d = 2.0f - 2.0f * vals[i];
        if (d <= fb + TAU) {
            const int p = atomicAdd(&s_cnt, 1);
            if (p < 128) s_cand[p] = ((i >> 2) * 256 + t) * 4 + (i & 3);
        }
    }
    __syncthreads();
    const int cnt = min(s_cnt, 128);
    if (cnt == 1) {
        if (t == 0) s_besti = s_cand[0];
    } else {
        if (t < cnt) {                 // exact rescore, sequential fma k=0..255
            const float* cb = cbn + (size_t)s_cand[t] * D_DIM;
            float acc = 0.0f;
            for (int k = 0; k < D_DIM; ++k) acc = fmaf(s_x[k], cb[k], acc);
            s_dex[t] = 2.0f - 2.0f * acc;
        }
        __syncthreads();
        if (t == 0) {                  // first-index tie-break
            float bdx = 3.402823466e+38f; int bii = 0x7fffffff;
            for (int c = 0; c < cnt; ++c) {
                const float d = s_dex[c]; const int ii = s_cand[c];
                if (d < bdx || (d == bdx && ii < bii)) { bdx = d; bii = ii; }
            }
            s_besti = bii;
        }
    }
    __syncthreads();
    const int besti = s_besti;

    // softmax: p_i = exp(20*(cos_i - M)) / sum
    float esum = 0.0f;
    #pragma unroll
    for (int i = 0; i < 16; ++i) {
        vals[i] = __expf(20.0f * (vals[i] - M));
        esum += vals[i];
    }
    #pragma unroll
    for (int off = 32; off > 0; off >>= 1) esum += __shfl_down(esum, off);
    __syncthreads();
    if ((t & 63) == 0) sf[t >> 6] = esum;
    __syncthreads();
    const float inv = 1.0f / (sf[0] + sf[1] + sf[2] + sf[3]);
    #pragma unroll
    for (int j = 0; j < 4; ++j) {
        rp[j * 256 + t] = make_float4(vals[j * 4 + 0] * inv, vals[j * 4 + 1] * inv,
                                      vals[j * 4 + 2] * inv, vals[j * 4 + 3] * inv);
    }

    // gather quantized row, per-row commitment loss
    const float q = cbn[(size_t)besti * D_DIM + t];
    xq[(size_t)row * D_DIM + t] = q;
    const float dd = q - s_x[t];
    float ls = dd * dd;
    #pragma unroll
    for (int off = 32; off > 0; off >>= 1) ls += __shfl_down(ls, off);
    __syncthreads();
    if ((t & 63) == 0) sf[t >> 6] = ls;
    __syncthreads();
    if (t == 0) {
        rowloss[row] = sf[0] + sf[1] + sf[2] + sf[3];
        idx_out[row] = (float)besti;
        atomicAdd(&counts[besti], 1.0f);
    }
}

// ---------------- finalize: vq_loss scalar + perplexity ----------------
__global__ __launch_bounds__(256) void finalize_kernel(
    const float* __restrict__ rowloss, const float* __restrict__ counts,
    float* __restrict__ out_loss, float* __restrict__ out_ppl)
{
    const int t = threadIdx.x;
    float s = 0.0f;
    for (int i = t; i < N_ROWS; i += 256) s += rowloss[i];
    float e = 0.0f;
    for (int i = t; i < K_CODES; i += 256) {
        const float avg = counts[i] * (1.0f / (float)N_ROWS);
        e += avg * logf(avg + 1e-10f);
    }
    #pragma unroll
    for (int off = 32; off > 0; off >>= 1) {
        s += __shfl_down(s, off);
        e += __shfl_down(e, off);
    }
    __shared__ float sf[4], se[4];
    if ((t & 63) == 0) { sf[t >> 6] = s; se[t >> 6] = e; }
    __syncthreads();
    if (t == 0) {
        out_loss[0] = 0.25f * (sf[0] + sf[1] + sf[2] + sf[3]) /
                      ((float)N_ROWS * (float)D_DIM);
        out_ppl[0] = expf(-(se[0] + se[1] + se[2] + se[3]));
    }
}

extern "C" void kernel_launch(void* const* d_in, const int* in_sizes, int n_in,
                              void* d_out, int out_size, void* d_ws, size_t ws_size,
                              hipStream_t stream) {
    const float* inputs   = (const float*)d_in[0];   // [N, D] raw
    const float* codebook = (const float*)d_in[1];   // [K, D] raw
    float* out = (float*)d_out;

    // output layout (flat, return order)
    float* vq_loss = out;                                   // 1
    float* quant   = out + 1;                               // N*D (also x_n scratch)
    float* probs   = quant + (size_t)N_ROWS * D_DIM;        // N*K
    float* ppl     = probs + (size_t)N_ROWS * K_CODES;      // 1
    float* idxout  = ppl + 1;                               // N

    // workspace layout (~25.3 MB)
    float* cbn     = (float*)d_ws;                          // K*D fp32
    float* counts  = cbn + (size_t)K_CODES * D_DIM;         // K
    float* rowloss = counts + K_CODES;                      // N
    unsigned short* Ah = (unsigned short*)(rowloss + N_ROWS);   // N*D bf16 hi
    unsigned short* Al = Ah + (size_t)N_ROWS * D_DIM;           // N*D bf16 lo
    unsigned short* Bh = Al + (size_t)N_ROWS * D_DIM;           // K*D bf16 hi
    unsigned short* Bl = Bh + (size_t)K_CODES * D_DIM;          // K*D bf16 lo

    hipMemsetAsync(counts, 0, K_CODES * sizeof(float), stream);
    norm_rows_np_kernel<<<K_CODES / NORM_ROWS_PER_BLK, 256, 0, stream>>>(codebook, cbn, Bh, Bl);
    norm_rows_np_kernel<<<N_ROWS / NORM_ROWS_PER_BLK, 256, 0, stream>>>(inputs, quant, Ah, Al);
    gemm_bf16x3_kernel<<<dim3(K_CODES / 128, N_ROWS / 128), 256, 0, stream>>>(Ah, Al, Bh, Bl, probs);
    rowpass_kernel<<<N_ROWS, 256, 0, stream>>>(probs, cbn, quant, idxout, counts, rowloss);
    finalize_kernel<<<1, 256, 0, stream>>>(rowloss, counts, vq_loss, ppl);
}